// Round 2
// baseline (17.249 us; speedup 1.0000x reference)
//
#include <hip/hip_runtime.h>
#include <math.h>

// Analytic reduction of the 5-wire QSP/LCU circuit:
//   out = Re[ 0.25 * (A_x1 + A_x2) * (A_t1 + A_t2) ]
//   A(ph, z) = <+| RZ(ph[n-1]) S(z) ... S(z) RZ(ph[0]) |+>  = 0.5 * sum_ij M_ij
//   S(z) = [[z, i*s],[i*s, z]], s = sqrt(1-z^2);  RZ(p) = diag(e^{-ip/2}, e^{ip/2})
//
// Phase sin/cos (uniform across the batch) computed once per block in LDS
// instead of 14 sincosf per thread.

__device__ __forceinline__ float2 cmul(float2 a, float2 b) {
    return make_float2(fmaf(a.x, b.x, -a.y * b.y), fmaf(a.x, b.y, a.y * b.x));
}

template <int N>
__device__ __forceinline__ float2 qsp_A(const float* c, const float* s,
                                        float z, float sz) {
    float2 m00 = make_float2(c[0], -s[0]);
    float2 m01 = make_float2(0.f, 0.f);
    float2 m10 = make_float2(0.f, 0.f);
    float2 m11 = make_float2(c[0],  s[0]);
#pragma unroll
    for (int k = 1; k < N; ++k) {
        // S * M
        float2 n00 = make_float2(z * m00.x - sz * m10.y, z * m00.y + sz * m10.x);
        float2 n01 = make_float2(z * m01.x - sz * m11.y, z * m01.y + sz * m11.x);
        float2 n10 = make_float2(z * m10.x - sz * m00.y, z * m10.y + sz * m00.x);
        float2 n11 = make_float2(z * m11.x - sz * m01.y, z * m11.y + sz * m01.x);
        // RZ(ph_k) * M'
        float2 e0 = make_float2(c[k], -s[k]);
        float2 e1 = make_float2(c[k],  s[k]);
        m00 = cmul(e0, n00); m01 = cmul(e0, n01);
        m10 = cmul(e1, n10); m11 = cmul(e1, n11);
    }
    return make_float2(0.5f * (m00.x + m01.x + m10.x + m11.x),
                       0.5f * (m00.y + m01.y + m10.y + m11.y));
}

struct Phases {
    float cx1[3], sx1[3], cx2[4], sx2[4];
    float ct1[3], st1[3], ct2[4], st2[4];
};

__device__ __forceinline__ float f_one(float tt, float xx, const Phases& P) {
    float sx = sqrtf(fmaxf(0.f, 1.f - xx * xx));
    float st = sqrtf(fmaxf(0.f, 1.f - tt * tt));
    float2 Ax1 = qsp_A<3>(P.cx1, P.sx1, xx, sx);
    float2 Ax2 = qsp_A<4>(P.cx2, P.sx2, xx, sx);
    float2 At1 = qsp_A<3>(P.ct1, P.st1, tt, st);
    float2 At2 = qsp_A<4>(P.ct2, P.st2, tt, st);
    float2 Ax = make_float2(Ax1.x + Ax2.x, Ax1.y + Ax2.y);
    float2 At = make_float2(At1.x + At2.x, At1.y + At2.y);
    return 0.25f * (Ax.x * At.x - Ax.y * At.y);
}

__global__ __launch_bounds__(256) void qpinn_kernel(
    const float* __restrict__ t, const float* __restrict__ x,
    const float* __restrict__ phx1, const float* __restrict__ phx2,
    const float* __restrict__ pht1, const float* __restrict__ pht2,
    float* __restrict__ out, int n) {
    __shared__ float sc[14], cc[14];
    int tid = threadIdx.x;
    if (tid < 14) {
        float p;
        if (tid < 3)       p = phx1[tid];
        else if (tid < 7)  p = phx2[tid - 3];
        else if (tid < 10) p = pht1[tid - 7];
        else               p = pht2[tid - 10];
        float s, c;
        sincosf(0.5f * p, &s, &c);
        sc[tid] = s; cc[tid] = c;
    }
    __syncthreads();

    Phases P;
#pragma unroll
    for (int k = 0; k < 3; ++k) { P.sx1[k] = sc[k];      P.cx1[k] = cc[k]; }
#pragma unroll
    for (int k = 0; k < 4; ++k) { P.sx2[k] = sc[3 + k];  P.cx2[k] = cc[3 + k]; }
#pragma unroll
    for (int k = 0; k < 3; ++k) { P.st1[k] = sc[7 + k];  P.ct1[k] = cc[7 + k]; }
#pragma unroll
    for (int k = 0; k < 4; ++k) { P.st2[k] = sc[10 + k]; P.ct2[k] = cc[10 + k]; }

    int i = blockIdx.x * blockDim.x + tid;
    int base = i * 2;
    if (base + 1 < n) {
        float2 tv = *reinterpret_cast<const float2*>(t + base);
        float2 xv = *reinterpret_cast<const float2*>(x + base);
        float2 ov;
        ov.x = f_one(tv.x, xv.x, P);
        ov.y = f_one(tv.y, xv.y, P);
        *reinterpret_cast<float2*>(out + base) = ov;
    } else if (base < n) {
        out[base] = f_one(t[base], x[base], P);
    }
}

extern "C" void kernel_launch(void* const* d_in, const int* in_sizes, int n_in,
                              void* d_out, int out_size, void* d_ws, size_t ws_size,
                              hipStream_t stream) {
    const float* t    = (const float*)d_in[0];
    const float* x    = (const float*)d_in[1];
    const float* phx1 = (const float*)d_in[2];
    const float* phx2 = (const float*)d_in[3];
    const float* pht1 = (const float*)d_in[4];
    const float* pht2 = (const float*)d_in[5];
    float* out = (float*)d_out;
    int n = out_size;  // 262144
    int groups = (n + 1) / 2;
    int block = 256;
    int grid = (groups + block - 1) / block;  // 512
    qpinn_kernel<<<grid, block, 0, stream>>>(t, x, phx1, phx2, pht1, pht2, out, n);
}

// Round 3
// 12.135 us; speedup vs baseline: 1.4214x; 1.4214x over previous
//
#include <hip/hip_runtime.h>
#include <math.h>

// Analytic reduction of the 5-wire QSP/LCU circuit:
//   out = Re[ 0.25 * (A_x1 + A_x2) * (A_t1 + A_t2) ]
//   A(ph, z) = <+| RZ(ph[n-1]) S(z) ... S(z) RZ(ph[0]) |+>  = 0.5 * sum_ij M_ij
//   S(z) = [[z, i*s],[i*s, z]], s = sqrt(1-z^2);  RZ(p) = diag(e^{-ip/2}, e^{ip/2})
//
// Round-1 structure (no LDS, no barrier — redundant uniform work hides under
// TLP). Phase trig via hardware v_sin/v_cos (__sinf/__cosf): args are
// 0.5*phi in [0, pi], no range reduction needed.

__device__ __forceinline__ float2 cmul(float2 a, float2 b) {
    return make_float2(fmaf(a.x, b.x, -a.y * b.y), fmaf(a.x, b.y, a.y * b.x));
}

template <int N>
__device__ __forceinline__ float2 qsp_A(const float* c, const float* s,
                                        float z, float sz) {
    float2 m00 = make_float2(c[0], -s[0]);
    float2 m01 = make_float2(0.f, 0.f);
    float2 m10 = make_float2(0.f, 0.f);
    float2 m11 = make_float2(c[0],  s[0]);
#pragma unroll
    for (int k = 1; k < N; ++k) {
        // S * M
        float2 n00 = make_float2(z * m00.x - sz * m10.y, z * m00.y + sz * m10.x);
        float2 n01 = make_float2(z * m01.x - sz * m11.y, z * m01.y + sz * m11.x);
        float2 n10 = make_float2(z * m10.x - sz * m00.y, z * m10.y + sz * m00.x);
        float2 n11 = make_float2(z * m11.x - sz * m01.y, z * m11.y + sz * m01.x);
        // RZ(ph_k) * M'
        float2 e0 = make_float2(c[k], -s[k]);
        float2 e1 = make_float2(c[k],  s[k]);
        m00 = cmul(e0, n00); m01 = cmul(e0, n01);
        m10 = cmul(e1, n10); m11 = cmul(e1, n11);
    }
    return make_float2(0.5f * (m00.x + m01.x + m10.x + m11.x),
                       0.5f * (m00.y + m01.y + m10.y + m11.y));
}

struct Phases {
    float cx1[3], sx1[3], cx2[4], sx2[4];
    float ct1[3], st1[3], ct2[4], st2[4];
};

__device__ __forceinline__ float f_one(float tt, float xx, const Phases& P) {
    float sx = sqrtf(fmaxf(0.f, 1.f - xx * xx));
    float st = sqrtf(fmaxf(0.f, 1.f - tt * tt));
    float2 Ax1 = qsp_A<3>(P.cx1, P.sx1, xx, sx);
    float2 Ax2 = qsp_A<4>(P.cx2, P.sx2, xx, sx);
    float2 At1 = qsp_A<3>(P.ct1, P.st1, tt, st);
    float2 At2 = qsp_A<4>(P.ct2, P.st2, tt, st);
    float2 Ax = make_float2(Ax1.x + Ax2.x, Ax1.y + Ax2.y);
    float2 At = make_float2(At1.x + At2.x, At1.y + At2.y);
    return 0.25f * (Ax.x * At.x - Ax.y * At.y);
}

__global__ __launch_bounds__(256) void qpinn_kernel(
    const float* __restrict__ t, const float* __restrict__ x,
    const float* __restrict__ phx1, const float* __restrict__ phx2,
    const float* __restrict__ pht1, const float* __restrict__ pht2,
    float* __restrict__ out, int n) {
    int i = blockIdx.x * blockDim.x + threadIdx.x;  // 4 elements per thread

    Phases P;
#pragma unroll
    for (int k = 0; k < 3; ++k) {
        float a = 0.5f * phx1[k];
        P.sx1[k] = __sinf(a); P.cx1[k] = __cosf(a);
    }
#pragma unroll
    for (int k = 0; k < 4; ++k) {
        float a = 0.5f * phx2[k];
        P.sx2[k] = __sinf(a); P.cx2[k] = __cosf(a);
    }
#pragma unroll
    for (int k = 0; k < 3; ++k) {
        float a = 0.5f * pht1[k];
        P.st1[k] = __sinf(a); P.ct1[k] = __cosf(a);
    }
#pragma unroll
    for (int k = 0; k < 4; ++k) {
        float a = 0.5f * pht2[k];
        P.st2[k] = __sinf(a); P.ct2[k] = __cosf(a);
    }

    int base = i * 4;
    if (base + 3 < n) {
        float4 tv = *reinterpret_cast<const float4*>(t + base);
        float4 xv = *reinterpret_cast<const float4*>(x + base);
        float4 ov;
        ov.x = f_one(tv.x, xv.x, P);
        ov.y = f_one(tv.y, xv.y, P);
        ov.z = f_one(tv.z, xv.z, P);
        ov.w = f_one(tv.w, xv.w, P);
        *reinterpret_cast<float4*>(out + base) = ov;
    } else {
        for (int j = base; j < n; ++j) out[j] = f_one(t[j], x[j], P);
    }
}

extern "C" void kernel_launch(void* const* d_in, const int* in_sizes, int n_in,
                              void* d_out, int out_size, void* d_ws, size_t ws_size,
                              hipStream_t stream) {
    const float* t    = (const float*)d_in[0];
    const float* x    = (const float*)d_in[1];
    const float* phx1 = (const float*)d_in[2];
    const float* phx2 = (const float*)d_in[3];
    const float* pht1 = (const float*)d_in[4];
    const float* pht2 = (const float*)d_in[5];
    float* out = (float*)d_out;
    int n = out_size;  // 262144
    int groups = (n + 3) / 4;
    int block = 256;
    int grid = (groups + block - 1) / block;  // 256
    qpinn_kernel<<<grid, block, 0, stream>>>(t, x, phx1, phx2, pht1, pht2, out, n);
}

// Round 4
// 9.700 us; speedup vs baseline: 1.7783x; 1.2511x over previous
//
#include <hip/hip_runtime.h>
#include <math.h>

// Analytic reduction of the 5-wire QSP/LCU circuit:
//   out = Re[ 0.25 * (A_x1 + A_x2) * (A_t1 + A_t2) ]
//   A(ph, z) = <+| RZ(ph[n-1]) S(z) ... S(z) RZ(ph[0]) |+>
// Propagated as the 2-vector v = M*(1,1)^T (A = 0.5*(v0+v1)) — half the
// arithmetic of the 2x2-matrix recursion.
//   S(z) = [[z, i*sz],[i*sz, z]], sz = sqrt(1-z^2); RZ(p) = diag(e^{-ip/2}, e^{ip/2})

__device__ __forceinline__ float2 cmul(float2 a, float2 b) {
    return make_float2(fmaf(a.x, b.x, -a.y * b.y), fmaf(a.x, b.y, a.y * b.x));
}

template <int N>
__device__ __forceinline__ float2 qsp_A(const float* c, const float* s,
                                        float z, float sz) {
    // v = RZ(ph0) * (1,1)^T
    float2 v0 = make_float2(c[0], -s[0]);
    float2 v1 = make_float2(c[0],  s[0]);
#pragma unroll
    for (int k = 1; k < N; ++k) {
        // S * v: w0 = z*v0 + i*sz*v1 ; w1 = i*sz*v0 + z*v1
        float2 w0 = make_float2(fmaf(z, v0.x, -sz * v1.y), fmaf(z, v0.y, sz * v1.x));
        float2 w1 = make_float2(fmaf(z, v1.x, -sz * v0.y), fmaf(z, v1.y, sz * v0.x));
        // RZ(ph_k): v0 = (c - i s)*w0, v1 = (c + i s)*w1
        v0 = cmul(make_float2(c[k], -s[k]), w0);
        v1 = cmul(make_float2(c[k],  s[k]), w1);
    }
    return make_float2(0.5f * (v0.x + v1.x), 0.5f * (v0.y + v1.y));
}

struct Phases {
    float cx1[3], sx1[3], cx2[4], sx2[4];
    float ct1[3], st1[3], ct2[4], st2[4];
};

__device__ __forceinline__ float f_one(float tt, float xx, const Phases& P) {
    float sx = sqrtf(fmaxf(0.f, 1.f - xx * xx));
    float st = sqrtf(fmaxf(0.f, 1.f - tt * tt));
    float2 Ax1 = qsp_A<3>(P.cx1, P.sx1, xx, sx);
    float2 Ax2 = qsp_A<4>(P.cx2, P.sx2, xx, sx);
    float2 At1 = qsp_A<3>(P.ct1, P.st1, tt, st);
    float2 At2 = qsp_A<4>(P.ct2, P.st2, tt, st);
    float2 Ax = make_float2(Ax1.x + Ax2.x, Ax1.y + Ax2.y);
    float2 At = make_float2(At1.x + At2.x, At1.y + At2.y);
    return 0.25f * (Ax.x * At.x - Ax.y * At.y);
}

__global__ __launch_bounds__(256) void qpinn_kernel(
    const float* __restrict__ t, const float* __restrict__ x,
    const float* __restrict__ phx1, const float* __restrict__ phx2,
    const float* __restrict__ pht1, const float* __restrict__ pht2,
    float* __restrict__ out, int n) {
    int i = blockIdx.x * blockDim.x + threadIdx.x;  // 2 elements per thread

    Phases P;
#pragma unroll
    for (int k = 0; k < 3; ++k) sincosf(0.5f * phx1[k], &P.sx1[k], &P.cx1[k]);
#pragma unroll
    for (int k = 0; k < 4; ++k) sincosf(0.5f * phx2[k], &P.sx2[k], &P.cx2[k]);
#pragma unroll
    for (int k = 0; k < 3; ++k) sincosf(0.5f * pht1[k], &P.st1[k], &P.ct1[k]);
#pragma unroll
    for (int k = 0; k < 4; ++k) sincosf(0.5f * pht2[k], &P.st2[k], &P.ct2[k]);

    int base = i * 2;
    if (base + 1 < n) {
        float2 tv = *reinterpret_cast<const float2*>(t + base);
        float2 xv = *reinterpret_cast<const float2*>(x + base);
        float2 ov;
        ov.x = f_one(tv.x, xv.x, P);
        ov.y = f_one(tv.y, xv.y, P);
        *reinterpret_cast<float2*>(out + base) = ov;
    } else if (base < n) {
        out[base] = f_one(t[base], x[base], P);
    }
}

extern "C" void kernel_launch(void* const* d_in, const int* in_sizes, int n_in,
                              void* d_out, int out_size, void* d_ws, size_t ws_size,
                              hipStream_t stream) {
    const float* t    = (const float*)d_in[0];
    const float* x    = (const float*)d_in[1];
    const float* phx1 = (const float*)d_in[2];
    const float* phx2 = (const float*)d_in[3];
    const float* pht1 = (const float*)d_in[4];
    const float* pht2 = (const float*)d_in[5];
    float* out = (float*)d_out;
    int n = out_size;  // 262144
    int groups = (n + 1) / 2;
    int block = 256;
    int grid = (groups + block - 1) / block;  // 512
    qpinn_kernel<<<grid, block, 0, stream>>>(t, x, phx1, phx2, pht1, pht2, out, n);
}

// Round 5
// 9.478 us; speedup vs baseline: 1.8199x; 1.0234x over previous
//
#include <hip/hip_runtime.h>
#include <math.h>

// Analytic reduction of the 5-wire QSP/LCU circuit:
//   out = Re[ 0.25 * (A_x1 + A_x2) * (A_t1 + A_t2) ]
//   A(ph, z) = <+| RZ(ph[n-1]) S(z) ... S(z) RZ(ph[0]) |+>
// Propagated as the 2-vector v = M*(1,1)^T (A = 0.5*(v0+v1)).
//   S(z) = [[z, i*sz],[i*sz, z]], sz = sqrt(1-z^2); RZ(p) = diag(e^{-ip/2}, e^{ip/2})
//
// 1 element/thread (1024 blocks -> 4 waves/SIMD) to hide the ~40-deep
// dependent FMA chain; hardware trig (__sinf, args in [0,pi]) for the
// uniform phase preamble.

__device__ __forceinline__ float2 cmul(float2 a, float2 b) {
    return make_float2(fmaf(a.x, b.x, -a.y * b.y), fmaf(a.x, b.y, a.y * b.x));
}

template <int N>
__device__ __forceinline__ float2 qsp_A(const float* c, const float* s,
                                        float z, float sz) {
    // v = RZ(ph0) * (1,1)^T
    float2 v0 = make_float2(c[0], -s[0]);
    float2 v1 = make_float2(c[0],  s[0]);
#pragma unroll
    for (int k = 1; k < N; ++k) {
        // S * v
        float2 w0 = make_float2(fmaf(z, v0.x, -sz * v1.y), fmaf(z, v0.y, sz * v1.x));
        float2 w1 = make_float2(fmaf(z, v1.x, -sz * v0.y), fmaf(z, v1.y, sz * v0.x));
        // RZ(ph_k)
        v0 = cmul(make_float2(c[k], -s[k]), w0);
        v1 = cmul(make_float2(c[k],  s[k]), w1);
    }
    return make_float2(0.5f * (v0.x + v1.x), 0.5f * (v0.y + v1.y));
}

struct Phases {
    float cx1[3], sx1[3], cx2[4], sx2[4];
    float ct1[3], st1[3], ct2[4], st2[4];
};

__device__ __forceinline__ float f_one(float tt, float xx, const Phases& P) {
    float sx = sqrtf(fmaxf(0.f, 1.f - xx * xx));
    float st = sqrtf(fmaxf(0.f, 1.f - tt * tt));
    float2 Ax1 = qsp_A<3>(P.cx1, P.sx1, xx, sx);
    float2 Ax2 = qsp_A<4>(P.cx2, P.sx2, xx, sx);
    float2 At1 = qsp_A<3>(P.ct1, P.st1, tt, st);
    float2 At2 = qsp_A<4>(P.ct2, P.st2, tt, st);
    float2 Ax = make_float2(Ax1.x + Ax2.x, Ax1.y + Ax2.y);
    float2 At = make_float2(At1.x + At2.x, At1.y + At2.y);
    return 0.25f * (Ax.x * At.x - Ax.y * At.y);
}

__global__ __launch_bounds__(256) void qpinn_kernel(
    const float* __restrict__ t, const float* __restrict__ x,
    const float* __restrict__ phx1, const float* __restrict__ phx2,
    const float* __restrict__ pht1, const float* __restrict__ pht2,
    float* __restrict__ out, int n) {
    int i = blockIdx.x * blockDim.x + threadIdx.x;  // 1 element per thread

    Phases P;
#pragma unroll
    for (int k = 0; k < 3; ++k) {
        float a = 0.5f * phx1[k];
        P.sx1[k] = __sinf(a); P.cx1[k] = __cosf(a);
    }
#pragma unroll
    for (int k = 0; k < 4; ++k) {
        float a = 0.5f * phx2[k];
        P.sx2[k] = __sinf(a); P.cx2[k] = __cosf(a);
    }
#pragma unroll
    for (int k = 0; k < 3; ++k) {
        float a = 0.5f * pht1[k];
        P.st1[k] = __sinf(a); P.ct1[k] = __cosf(a);
    }
#pragma unroll
    for (int k = 0; k < 4; ++k) {
        float a = 0.5f * pht2[k];
        P.st2[k] = __sinf(a); P.ct2[k] = __cosf(a);
    }

    if (i < n) {
        out[i] = f_one(t[i], x[i], P);
    }
}

extern "C" void kernel_launch(void* const* d_in, const int* in_sizes, int n_in,
                              void* d_out, int out_size, void* d_ws, size_t ws_size,
                              hipStream_t stream) {
    const float* t    = (const float*)d_in[0];
    const float* x    = (const float*)d_in[1];
    const float* phx1 = (const float*)d_in[2];
    const float* phx2 = (const float*)d_in[3];
    const float* pht1 = (const float*)d_in[4];
    const float* pht2 = (const float*)d_in[5];
    float* out = (float*)d_out;
    int n = out_size;  // 262144
    int block = 256;
    int grid = (n + block - 1) / block;  // 1024
    qpinn_kernel<<<grid, block, 0, stream>>>(t, x, phx1, phx2, pht1, pht2, out, n);
}